// Round 2
// baseline (8816.779 us; speedup 1.0000x reference)
//
#include <hip/hip_runtime.h>
#include <hip/hip_bf16.h>

#define N_NODES 100000
#define N_EDGES 1600000
#define N_GRAPHS 1000
#define HID 64
#define GRP 10

// ---------- helpers ----------
__device__ __forceinline__ float bf1(unsigned short u){ union{unsigned int x; float f;} v; v.x = ((unsigned int)u)<<16; return v.f; }
__device__ __forceinline__ float bf_lo(unsigned int u){ union{unsigned int x; float f;} v; v.x = u<<16; return v.f; }
__device__ __forceinline__ float bf_hi(unsigned int u){ union{unsigned int x; float f;} v; v.x = u & 0xFFFF0000u; return v.f; }
__device__ __forceinline__ unsigned short f2bf(float f){
  union{float f; unsigned int i;} v; v.f = f;
  unsigned int r = v.i + 0x7FFFu + ((v.i >> 16) & 1u);
  return (unsigned short)(r >> 16);
}
__device__ __forceinline__ float eluf(float v){ return v > 0.f ? v : expm1f(v); }

// order-preserving float->uint encoding for atomicMax-based segment max
__device__ __forceinline__ unsigned int encf(float f){
  unsigned int u = __float_as_uint(f);
  return (u & 0x80000000u) ? ~u : (u | 0x80000000u);
}
__device__ __forceinline__ float decf(unsigned int u){
  unsigned int b = (u & 0x80000000u) ? (u & 0x7FFFFFFFu) : ~u;
  return __uint_as_float(b);
}

// ---------- weight transpose (f32 -> f32) ----------
struct CvtEnt { const float* s; float* d; int rows; int cols; };
struct CvtArgs { CvtEnt e[16]; int cnt; };

__global__ __launch_bounds__(256) void k_convert(CvtArgs a){
  CvtEnt E = a.e[blockIdx.y];
  int n = E.rows * E.cols;
  for (int i = blockIdx.x*256 + threadIdx.x; i < n; i += gridDim.x*256){
    int r = i / E.cols, c = i % E.cols;
    E.d[(size_t)c*E.rows + r] = E.s[i];
  }
}

// ---------- generic linear: out[n,0..63] = act(A[n,:] @ W + b) ----------
// WT is [64][K] (transposed, f32). Thread-per-row; weight reads are uniform -> s_load.
template<int K, int RELU, int INBF, int OUTBF, int HASB>
__global__ __launch_bounds__(256) void k_linear64(const void* Ap,
    const float* __restrict__ WT, const float* __restrict__ bias, void* Op, int N)
{
  int n = blockIdx.x*256 + threadIdx.x;
  if (n >= N) return;
  float a[K];
  if constexpr (INBF){
    const unsigned int* p = (const unsigned int*)((const unsigned short*)Ap + (size_t)n*K);
    #pragma unroll
    for (int i=0;i<K/2;i++){ unsigned int u=p[i]; a[2*i]=bf_lo(u); a[2*i+1]=bf_hi(u); }
  } else if constexpr (K % 4 == 0){
    const float4* p = (const float4*)((const float*)Ap + (size_t)n*K);
    #pragma unroll
    for (int i=0;i<K/4;i++){ float4 v=p[i]; a[4*i]=v.x; a[4*i+1]=v.y; a[4*i+2]=v.z; a[4*i+3]=v.w; }
  } else {
    const float2* p = (const float2*)((const float*)Ap + (size_t)n*K);
    #pragma unroll
    for (int i=0;i<K/2;i++){ float2 v=p[i]; a[2*i]=v.x; a[2*i+1]=v.y; }
  }
  for (int c=0;c<64;c+=4){
    float s0 = HASB ? bias[c+0] : 0.f;
    float s1 = HASB ? bias[c+1] : 0.f;
    float s2 = HASB ? bias[c+2] : 0.f;
    float s3 = HASB ? bias[c+3] : 0.f;
    const float* w = WT + (size_t)c*K;
    #pragma unroll
    for (int k=0;k<K;k++){
      float av = a[k];
      s0 = fmaf(av, w[k],     s0);
      s1 = fmaf(av, w[K+k],   s1);
      s2 = fmaf(av, w[2*K+k], s2);
      s3 = fmaf(av, w[3*K+k], s3);
    }
    if (RELU){ s0=fmaxf(s0,0.f); s1=fmaxf(s1,0.f); s2=fmaxf(s2,0.f); s3=fmaxf(s3,0.f); }
    if constexpr (OUTBF){
      uint2 uu;
      uu.x = ((unsigned int)f2bf(s1)<<16) | f2bf(s0);
      uu.y = ((unsigned int)f2bf(s3)<<16) | f2bf(s2);
      *(uint2*)((unsigned short*)Op + (size_t)n*64 + c) = uu;
    } else {
      float4 r; r.x=s0; r.y=s1; r.z=s2; r.w=s3;
      *(float4*)((float*)Op + (size_t)n*64 + c) = r;
    }
  }
}

// ---------- GATv2 edge passes ----------
// wave-per-edge: logit = att . leaky(xl[src]+xr[dst](+emb)); atomicMax per segment
__global__ __launch_bounds__(256) void k_edge_logit(
  const int* __restrict__ src, const int* __restrict__ dst,
  const float* __restrict__ xl, const float* __restrict__ xr,
  const unsigned short* __restrict__ emb, const float* __restrict__ att,
  float* __restrict__ logits, unsigned int* __restrict__ nmax, int nE)
{
  int lane = threadIdx.x & 63;
  float av = att[lane];
  int wid = (blockIdx.x*256 + threadIdx.x) >> 6;
  int nw  = (gridDim.x*256) >> 6;
  for (int e = wid; e < nE; e += nw){
    int sN = src ? src[e] : e;
    int dN = dst[e];
    float v = xl[(size_t)sN*64 + lane] + xr[(size_t)dN*64 + lane];
    if (emb) v += bf1(emb[(size_t)e*64 + lane]);
    v = v > 0.f ? v : 0.01f*v;
    float p = v * av;
    #pragma unroll
    for (int o=32;o;o>>=1) p += __shfl_xor(p, o, 64);
    if (lane == 0){
      logits[e] = p;
      atomicMax(nmax + dN, encf(p));
    }
  }
}

__global__ __launch_bounds__(256) void k_edge_exp(
  const int* __restrict__ dst, const float* __restrict__ logits,
  const unsigned int* __restrict__ nmax, float* __restrict__ w,
  float* __restrict__ nsum, int nE)
{
  int e = blockIdx.x*256 + threadIdx.x;
  if (e >= nE) return;
  int d = dst[e];
  float m = decf(nmax[d]);
  float ww = expf(logits[e] - m);
  w[e] = ww;
  atomicAdd(nsum + d, ww);
}

__global__ __launch_bounds__(256) void k_edge_agg(
  const int* __restrict__ src, const int* __restrict__ dst,
  const float* __restrict__ xl, const float* __restrict__ w,
  const float* __restrict__ nsum, float* __restrict__ agg, int nE)
{
  int lane = threadIdx.x & 63;
  int wid = (blockIdx.x*256 + threadIdx.x) >> 6;
  int nw  = (gridDim.x*256) >> 6;
  for (int e = wid; e < nE; e += nw){
    int sN = src ? src[e] : e;
    int dN = dst[e];
    float a = w[e] / (nsum[dN] + 1e-16f);
    atomicAdd(agg + (size_t)dN*64 + lane, xl[(size_t)sN*64 + lane] * a);
  }
}

// ---------- GRU (fuses h = elu(agg + gat_bias); writes relu(gru) in-place into x) ----------
__global__ __launch_bounds__(256) void k_gru(const float* __restrict__ agg,
  const float* __restrict__ gatb, float* x,
  const float* __restrict__ Wih, const float* __restrict__ Whh,
  const float* __restrict__ bih, const float* __restrict__ bhh, int N)
{
  int n = blockIdx.x*256 + threadIdx.x;
  if (n >= N) return;
  float h[64], xv[64];
  const float4* pa = (const float4*)(agg + (size_t)n*64);
  const float4* px = (const float4*)(x   + (size_t)n*64);
  #pragma unroll
  for (int i=0;i<16;i++){
    float4 avv = pa[i]; float4 xx = px[i];
    h[4*i+0]=eluf(avv.x + gatb[4*i+0]);
    h[4*i+1]=eluf(avv.y + gatb[4*i+1]);
    h[4*i+2]=eluf(avv.z + gatb[4*i+2]);
    h[4*i+3]=eluf(avv.w + gatb[4*i+3]);
    xv[4*i+0]=xx.x; xv[4*i+1]=xx.y; xv[4*i+2]=xx.z; xv[4*i+3]=xx.w;
  }
  for (int c=0;c<64;c++){
    float ir=bih[c], iz=bih[64+c], in2=bih[128+c];
    float hr=bhh[c], hz=bhh[64+c], hn=bhh[128+c];
    const float* wi = Wih + (size_t)c*64;
    const float* wh = Whh + (size_t)c*64;
    #pragma unroll
    for (int k=0;k<64;k++){
      float hk = h[k], xk = xv[k];
      ir  = fmaf(hk, wi[k],      ir);
      iz  = fmaf(hk, wi[4096+k], iz);
      in2 = fmaf(hk, wi[8192+k], in2);
      hr  = fmaf(xk, wh[k],      hr);
      hz  = fmaf(xk, wh[4096+k], hz);
      hn  = fmaf(xk, wh[8192+k], hn);
    }
    float r = 1.f/(1.f + expf(-(ir+hr)));
    float z = 1.f/(1.f + expf(-(iz+hz)));
    float nn = tanhf(in2 + r*hn);
    float o = (1.f - z)*nn + z*xv[c];
    x[(size_t)n*64 + c] = fmaxf(o, 0.f);
  }
}

// ---------- DiffGroupNorm ----------
__global__ __launch_bounds__(256) void k_dgn_s(const float* __restrict__ x,
  const float* __restrict__ WT /*10x64*/, const float* __restrict__ b,
  float* __restrict__ s, int N)
{
  int n = blockIdx.x*256 + threadIdx.x;
  if (n >= N) return;
  float a[64];
  const float4* p = (const float4*)(x + (size_t)n*64);
  #pragma unroll
  for (int i=0;i<16;i++){ float4 v=p[i]; a[4*i]=v.x; a[4*i+1]=v.y; a[4*i+2]=v.z; a[4*i+3]=v.w; }
  float lg[10];
  #pragma unroll
  for (int g=0; g<10; g++){
    float acc = b[g];
    const float* w = WT + (size_t)g*64;
    #pragma unroll
    for (int k=0;k<64;k++) acc = fmaf(a[k], w[k], acc);
    lg[g] = acc;
  }
  float m = lg[0];
  #pragma unroll
  for (int g=1;g<10;g++) m = fmaxf(m, lg[g]);
  float e[10], sum = 0.f;
  #pragma unroll
  for (int g=0;g<10;g++){ e[g] = expf(lg[g]-m); sum += e[g]; }
  float inv = 1.f/sum;
  #pragma unroll
  for (int g=0;g<10;g++) s[(size_t)n*10+g] = e[g]*inv;
}

__global__ __launch_bounds__(640) void k_dgn_stats(const float* __restrict__ s,
  const float* __restrict__ x, float* cs, float* cs2, int N)
{
  int g = threadIdx.x >> 6, f = threadIdx.x & 63;
  int per = (N + gridDim.x - 1) / gridDim.x;
  int n0 = blockIdx.x * per;
  int n1 = min(N, n0 + per);
  float a = 0.f, a2 = 0.f;
  for (int n = n0; n < n1; n++){
    float y = s[(size_t)n*10+g] * x[(size_t)n*64+f];
    a += y; a2 += y*y;
  }
  atomicAdd(&cs [g*64+f], a);
  atomicAdd(&cs2[g*64+f], a2);
}

__global__ void k_dgn_final(const float* cs, const float* cs2,
  const float* __restrict__ bw, const float* __restrict__ bb,
  float* scale, float* shiftsum, int N)
{
  __shared__ float sh[640];
  int i = threadIdx.x;
  float invN = 1.f / (float)N;
  float mean = cs[i]*invN;
  float var  = cs2[i]*invN - mean*mean;
  float sc = bw[i] / sqrtf(var + 1e-5f);
  scale[i] = sc;
  sh[i] = bb[i] - mean*sc;
  __syncthreads();
  if (i < 64){
    float t = 0.f;
    #pragma unroll
    for (int g=0;g<10;g++) t += sh[g*64+i];
    shiftsum[i] = t;
  }
}

__global__ __launch_bounds__(256) void k_dgn_apply(float* x,
  const float* __restrict__ s, const float* __restrict__ scale,
  const float* __restrict__ shiftsum, int N)
{
  int idx = blockIdx.x*256 + threadIdx.x;
  if (idx >= N*64) return;
  int n = idx >> 6, f = idx & 63;
  float ss = 0.f;
  #pragma unroll
  for (int g=0; g<10; g++) ss = fmaf(s[(size_t)n*10+g], scale[g*64+f], ss);
  float xvv = x[idx];
  x[idx] = xvv + 0.01f*(xvv*ss + shiftsum[f]);
}

// ---------- readout ----------
__global__ __launch_bounds__(256) void k_segsum(const float* __restrict__ x,
  const int* __restrict__ batch, float* __restrict__ gout)
{
  int idx = blockIdx.x*256 + threadIdx.x;
  if (idx >= N_NODES*64) return;
  int n = idx >> 6, c = idx & 63;
  atomicAdd(gout + (size_t)batch[n]*64 + c, x[idx]);
}

__global__ __launch_bounds__(256) void k_relu(float* p, int n){
  int i = blockIdx.x*256 + threadIdx.x;
  if (i < n) p[i] = fmaxf(p[i], 0.f);
}

__global__ __launch_bounds__(256) void k_head(const float* __restrict__ y,
  const float* __restrict__ w, const float* __restrict__ b,
  float* __restrict__ out, int N)
{
  int n = blockIdx.x*256 + threadIdx.x;
  if (n >= N) return;
  float acc = b[0];
  const float4* p = (const float4*)(y + (size_t)n*64);
  #pragma unroll
  for (int i=0;i<16;i++){
    float4 v = p[i];
    acc = fmaf(v.x, w[4*i+0], acc);
    acc = fmaf(v.y, w[4*i+1], acc);
    acc = fmaf(v.z, w[4*i+2], acc);
    acc = fmaf(v.w, w[4*i+3], acc);
  }
  out[n] = acc;
}

// ---------- host ----------
extern "C" void kernel_launch(void* const* d_in, const int* in_sizes, int n_in,
                              void* d_out, int out_size, void* d_ws, size_t ws_size,
                              hipStream_t stream) {
  (void)in_sizes; (void)n_in; (void)out_size; (void)ws_size;

  // ----- workspace layout -----
  char* base = (char*)d_ws; size_t off = 0;
  auto A = [&](size_t bytes)->void*{ void* p = base + off; off += (bytes + 255) & ~(size_t)255; return p; };
  unsigned short* e_emb = (unsigned short*)A((size_t)N_EDGES*64*2);   // bf16: e then e@We (in-place)
  float* xbuf   = (float*)A((size_t)N_NODES*64*4);
  float* xl     = (float*)A((size_t)N_NODES*64*4);
  float* xr     = (float*)A((size_t)N_NODES*64*4);
  float* agg    = (float*)A((size_t)N_NODES*64*4);
  float* logits = (float*)A((size_t)N_EDGES*4);
  float* wexp   = (float*)A((size_t)N_EDGES*4);
  unsigned int* nmax = (unsigned int*)A((size_t)N_NODES*4);
  float* nsum   = (float*)A((size_t)N_NODES*4);
  float* sbuf   = (float*)A((size_t)N_NODES*10*4);
  float* gout   = (float*)A((size_t)N_GRAPHS*64*4);
  float* ybuf   = (float*)A((size_t)N_GRAPHS*64*4);
  float* ybuf2  = (float*)A((size_t)N_GRAPHS*64*4);
  float* colsum = (float*)A(2*640*4); float* colsumsq = colsum + 640;
  float* scale  = (float*)A((640+64)*4); float* shiftsum = scale + 640;
  float* wf     = (float*)A(60000*4);
  size_t wo = 0;
  auto W = [&](size_t n)->float*{ float* p = wf + wo; wo += n; return p; };

  float* pre_nWT = W(64*92);
  float* pre_eWT = W(64*50);
  float* WeT[2] = {W(4096), W(4096)};
  float* WlT[2] = {W(4096), W(4096)};
  float* WrT[2] = {W(4096), W(4096)};
  float* gnWT[2] = {W(640), W(640)};
  float* gWlT = W(4096);
  float* gWrT = W(4096);
  float* ggnWT = W(640);
  float* postWT[2] = {W(4096), W(4096)};

  const float* F[48];
  for (int i=0;i<41;i++) F[i] = (const float*)d_in[i];

  // ----- transpose table -----
  CvtArgs ca; ca.cnt = 0;
  auto addT = [&](const float* s, float* d, int r, int c){
    ca.e[ca.cnt].s=s; ca.e[ca.cnt].d=d; ca.e[ca.cnt].rows=r; ca.e[ca.cnt].cols=c; ca.cnt++; };

  addT(F[4],  pre_nWT, 92, 64);
  addT(F[6],  pre_eWT, 50, 64);
  for (int l=0;l<2;l++) addT(F[8]  + l*4096, WlT[l], 64, 64);
  for (int l=0;l<2;l++) addT(F[10] + l*4096, WrT[l], 64, 64);
  for (int l=0;l<2;l++) addT(F[12] + l*4096, WeT[l], 64, 64);
  for (int l=0;l<2;l++) addT(F[19] + l*640,  gnWT[l], 64, 10);
  addT(F[23], gWlT, 64, 64);
  addT(F[25], gWrT, 64, 64);
  addT(F[33], ggnWT, 64, 10);
  for (int l=0;l<2;l++) addT(F[37] + l*4096, postWT[l], 64, 64);

  const int* src   = (const int*)d_in[1];
  const int* dst   = src + N_EDGES;
  const int* batch = (const int*)d_in[3];

  const int NBn = (N_NODES + 255)/256;    // 391
  const int NBe = N_EDGES/256;            // 6250
  const int NBg = (N_GRAPHS + 255)/256;   // 4
  const int NBa = (N_NODES*64)/256;       // 25000

  k_convert<<<dim3(24, ca.cnt), 256, 0, stream>>>(ca);

  // x = relu(x_in @ pre_nW + pre_nb)
  k_linear64<92,1,0,0,1><<<NBn,256,0,stream>>>(F[0], pre_nWT, F[5], xbuf, N_NODES);

  for (int l=0; l<2; l++){
    // e = relu(edge_attr @ pre_eW + pre_eb)  (bf16 out), then e_emb = e @ We[l] in-place
    k_linear64<50,1,0,1,1><<<NBe,256,0,stream>>>(F[2], pre_eWT, F[7], e_emb, N_EDGES);
    k_linear64<64,0,1,1,0><<<NBe,256,0,stream>>>(e_emb, WeT[l], nullptr, e_emb, N_EDGES);

    for (int t=0; t<2; t++){
      k_linear64<64,0,0,0,1><<<NBn,256,0,stream>>>(xbuf, WlT[l], F[9]  + l*64, xl, N_NODES);
      k_linear64<64,0,0,0,1><<<NBn,256,0,stream>>>(xbuf, WrT[l], F[11] + l*64, xr, N_NODES);
      hipMemsetAsync(nmax, 0, (size_t)N_NODES*4, stream);
      hipMemsetAsync(nsum, 0, (size_t)N_NODES*4, stream);
      hipMemsetAsync(agg,  0, (size_t)N_NODES*64*4, stream);
      k_edge_logit<<<4096,256,0,stream>>>(src, dst, xl, xr, e_emb, F[13] + l*64, logits, nmax, N_EDGES);
      k_edge_exp<<<NBe,256,0,stream>>>(dst, logits, nmax, wexp, nsum, N_EDGES);
      k_edge_agg<<<4096,256,0,stream>>>(src, dst, xl, wexp, nsum, agg, N_EDGES);
      k_gru<<<NBn,256,0,stream>>>(agg, F[14] + l*64, xbuf, F[15] + l*12288, F[16] + l*12288,
                                  F[17] + l*192, F[18] + l*192, N_NODES);
    }
    hipMemsetAsync(colsum, 0, 2*640*4, stream);
    k_dgn_s<<<NBn,256,0,stream>>>(xbuf, gnWT[l], F[20] + l*10, sbuf, N_NODES);
    k_dgn_stats<<<128,640,0,stream>>>(sbuf, xbuf, colsum, colsumsq, N_NODES);
    k_dgn_final<<<1,640,0,stream>>>(colsum, colsumsq, F[21] + l*640, F[22] + l*640, scale, shiftsum, N_NODES);
    k_dgn_apply<<<NBa,256,0,stream>>>(xbuf, sbuf, scale, shiftsum, N_NODES);
  }

  // readout: out = relu(segment_sum(x, batch))
  hipMemsetAsync(gout, 0, (size_t)N_GRAPHS*64*4, stream);
  k_segsum<<<NBa,256,0,stream>>>(xbuf, batch, gout);
  k_relu<<<(N_GRAPHS*64+255)/256,256,0,stream>>>(gout, N_GRAPHS*64);

  // xl_g fixed across both timesteps (x doesn't change here)
  k_linear64<64,0,0,0,1><<<NBn,256,0,stream>>>(xbuf, gWlT, F[24], xl, N_NODES);
  for (int t=0; t<2; t++){
    k_linear64<64,0,0,0,1><<<NBg,256,0,stream>>>(gout, gWrT, F[26], xr, N_GRAPHS);
    hipMemsetAsync(nmax, 0, (size_t)N_GRAPHS*4, stream);
    hipMemsetAsync(nsum, 0, (size_t)N_GRAPHS*4, stream);
    hipMemsetAsync(agg,  0, (size_t)N_GRAPHS*64*4, stream);
    k_edge_logit<<<1024,256,0,stream>>>(nullptr, batch, xl, xr, nullptr, F[27], logits, nmax, N_NODES);
    k_edge_exp<<<NBn,256,0,stream>>>(batch, logits, nmax, wexp, nsum, N_NODES);
    k_edge_agg<<<1024,256,0,stream>>>(nullptr, batch, xl, wexp, nsum, agg, N_NODES);
    k_gru<<<NBg,256,0,stream>>>(agg, F[28], gout, F[29], F[30], F[31], F[32], N_GRAPHS);
  }

  hipMemsetAsync(colsum, 0, 2*640*4, stream);
  k_dgn_s<<<NBg,256,0,stream>>>(gout, ggnWT, F[34], sbuf, N_GRAPHS);
  k_dgn_stats<<<8,640,0,stream>>>(sbuf, gout, colsum, colsumsq, N_GRAPHS);
  k_dgn_final<<<1,640,0,stream>>>(colsum, colsumsq, F[35], F[36], scale, shiftsum, N_GRAPHS);
  k_dgn_apply<<<(N_GRAPHS*64+255)/256,256,0,stream>>>(gout, sbuf, scale, shiftsum, N_GRAPHS);

  // post MLP + head
  k_linear64<64,1,0,0,1><<<NBg,256,0,stream>>>(gout, postWT[0], F[38],      ybuf,  N_GRAPHS);
  k_linear64<64,1,0,0,1><<<NBg,256,0,stream>>>(ybuf, postWT[1], F[38] + 64, ybuf2, N_GRAPHS);
  k_head<<<NBg,256,0,stream>>>(ybuf2, F[39], F[40], (float*)d_out, N_GRAPHS);
}